// Round 8
// baseline (534.435 us; speedup 1.0000x reference)
//
#include <hip/hip_runtime.h>

// UpBlock: deconv(8-oct GEMM) -> BN+ELU -> 27-tap gather conv -> BN+ELU
// R8: per-channel y quantization folded into int8 W (no per-row scales -> no
// scale transactions, halves L2 transaction count); conv accumulates i32 in
// MFMA C operand (no per-tap dequant VALU); column factor T_d cancels in BN2.

#define N_PARENT 65536
#define C_IN     128
#define C_OUT    64
#define N_CHILD  (N_PARENT * 8)
#define TAPS     27
#define NBINS    64

typedef __bf16 bf16x8 __attribute__((ext_vector_type(8)));
typedef float  f32x4  __attribute__((ext_vector_type(4)));
typedef int    i32x4  __attribute__((ext_vector_type(4)));

// workspace layout (bytes)
#define Y_OFF     0u          // rows [N_CHILD][128B]: bf16 h, then int8 y8 in first 64B
#define WTUP_OFF  67108864u   // bf16 WtUp [8][64 n][128 k] = 131072
#define W8CV_OFF  67239936u   // i8 Wt8 [27][64 d][64 c] = 110592
#define CHMAX_OFF 67350528u   // u32 keyed per-channel max of f [64] = 256
#define SINV_OFF  67350784u   // f32 127/chabs [64] = 256
#define S1_OFF    67351040u   // f32 bins1 [64][128] = 32768
#define S2_OFF    67383808u   // f32 bins2 [64][128] = 32768
#define AB1_OFF   67416576u   // f32 a1[64], b1[64] = 512
#define AB2_OFF   67417088u   // f32 a2[64], b2[64] = 512
#define ZERO_LEN  (67417600u - CHMAX_OFF)

__device__ __forceinline__ float elu_f(float f) {
    return f > 0.f ? f : (__expf(f) - 1.f);
}
// order-preserving float<->uint key for atomicMax on signed floats
__device__ __forceinline__ unsigned fkey(float f) {
    unsigned b = __float_as_uint(f);
    return (b & 0x80000000u) ? ~b : (b | 0x80000000u);
}
__device__ __forceinline__ float fdec(unsigned k) {
    unsigned b = (k & 0x80000000u) ? (k & 0x7fffffffu) : ~k;
    return __uint_as_float(b);
}

// ---- prep: WtUp transpose -> bf16 [8][64 n][128 k] ----
__global__ __launch_bounds__(256) void prep_wup(const float* __restrict__ wup,
                                                __bf16* __restrict__ wtup) {
    int i = blockIdx.x * 256 + threadIdx.x;        // 65536
    int o = i >> 13, rem = i & 8191, n = rem >> 7, k = rem & 127;
    wtup[i] = (__bf16)wup[o * 8192 + k * 64 + n];
}

// ---- kernel A: h[8p+oct] = x[p] @ W_up[oct] (bf16), accumulate BN1 stats ----
__global__ __launch_bounds__(256) void deconv_bn_stats(
    const float* __restrict__ x, const __bf16* __restrict__ wtup,
    __bf16* __restrict__ y, float* __restrict__ bins) {
    __shared__ float ssum[64], ssq[64];
    int tid = threadIdx.x;
    int wave = tid >> 6, lane = tid & 63, lr = lane & 15, lg = lane >> 4;
    int p0 = blockIdx.x * 16;

    if (tid < 64) { ssum[tid] = 0.f; ssq[tid] = 0.f; }

    const float* xrow = x + (size_t)(p0 + lr) * C_IN;
    bf16x8 afr[4];
#pragma unroll
    for (int ks = 0; ks < 4; ++ks) {
        const float* src = xrow + ks * 32 + lg * 8;
        f32x4 u0 = *(const f32x4*)(src);
        f32x4 u1 = *(const f32x4*)(src + 4);
        bf16x8 a;
#pragma unroll
        for (int i = 0; i < 4; ++i) { a[i] = (__bf16)u0[i]; a[4 + i] = (__bf16)u1[i]; }
        afr[ks] = a;
    }

    float lsum[4] = {0.f, 0.f, 0.f, 0.f}, lsq[4] = {0.f, 0.f, 0.f, 0.f};
#pragma unroll
    for (int oo = 0; oo < 2; ++oo) {
        int oct = wave * 2 + oo;
#pragma unroll
        for (int nt = 0; nt < 4; ++nt) {
            f32x4 acc = {0.f, 0.f, 0.f, 0.f};
#pragma unroll
            for (int ks = 0; ks < 4; ++ks) {
                const __bf16* bp = wtup + ((size_t)(oct * 64 + nt * 16 + lr) * C_IN + ks * 32 + lg * 8);
                bf16x8 b = *(const bf16x8*)bp;
                acc = __builtin_amdgcn_mfma_f32_16x16x32_bf16(afr[ks], b, acc, 0, 0, 0);
            }
#pragma unroll
            for (int r = 0; r < 4; ++r) {
                int parent = p0 + lg * 4 + r;
                int child = parent * 8 + oct;
                float v = acc[r];
                y[(size_t)child * 64 + nt * 16 + lr] = (__bf16)v;
                lsum[nt] += v; lsq[nt] += v * v;
            }
        }
    }
    __syncthreads();
#pragma unroll
    for (int nt = 0; nt < 4; ++nt) {
        atomicAdd(&ssum[nt * 16 + lr], lsum[nt]);
        atomicAdd(&ssq[nt * 16 + lr], lsq[nt]);
    }
    __syncthreads();
    if (tid < 64) {
        float* b = bins + (size_t)(blockIdx.x & (NBINS - 1)) * 128;
        atomicAdd(&b[tid], ssum[tid]);
        atomicAdd(&b[64 + tid], ssq[tid]);
    }
}

// ---- finalize: per-channel a = gamma*rstd, b = beta - mu*a ----
__global__ void finalize_stats(const float* __restrict__ bins,
                               const float* __restrict__ gamma,
                               const float* __restrict__ beta,
                               float* __restrict__ ab, float invN) {
    int c = threadIdx.x;  // 64 threads
    float s = 0.f, q = 0.f;
    for (int b = 0; b < NBINS; ++b) { s += bins[b * 128 + c]; q += bins[b * 128 + 64 + c]; }
    float mu = s * invN;
    float var = q * invN - mu * mu;
    float rstd = rsqrtf(var + 1e-5f);
    float a = gamma[c] * rstd;
    ab[c] = a;
    ab[64 + c] = beta[c] - mu * a;
}

// ---- bn_max: per-channel signed max of f = h*a+b (for quant range) ----
// chabs = max(fmax, 1) bounds |ELU| on both sides (|ELU(neg)| < 1).
__global__ __launch_bounds__(256) void bn_max(const __bf16* __restrict__ y,
                                              const float* __restrict__ ab,
                                              unsigned* __restrict__ chmax) {
    __shared__ unsigned smax[64];
    int tid = threadIdx.x;
    if (tid < 64) smax[tid] = 0u;
    __syncthreads();
    int gt = blockIdx.x * 256 + tid;
    int c0 = (gt * 8) & 63;
    float av[8], bv[8], mx[8];
#pragma unroll
    for (int j = 0; j < 8; ++j) {
        av[j] = ab[c0 + j]; bv[j] = ab[64 + c0 + j]; mx[j] = -3e38f;
    }
#pragma unroll
    for (int t = 0; t < 4; ++t) {
        size_t e = ((size_t)t * 1048576 + gt) * 8;
        bf16x8 v = *(const bf16x8*)(y + e);
#pragma unroll
        for (int j = 0; j < 8; ++j) {
            float f = (float)v[j] * av[j] + bv[j];
            mx[j] = fmaxf(mx[j], f);
        }
    }
#pragma unroll
    for (int j = 0; j < 8; ++j) atomicMax(&smax[c0 + j], fkey(mx[j]));
    __syncthreads();
    if (tid < 64) atomicMax(&chmax[tid], smax[tid]);
}

// ---- prep_w8: fold per-channel y scale s_c into int8 W_conv ----
// w8[k][d][c] = round(wcv[k][c][d] * s_c * T_d); T_d cancels in BN2.
__global__ __launch_bounds__(256) void prep_w8(const float* __restrict__ wcv,
                                               const unsigned* __restrict__ chmax,
                                               signed char* __restrict__ w8,
                                               float* __restrict__ sinv) {
    __shared__ float scl[64];
    __shared__ float red[4];
    __shared__ float tds;
    int d = blockIdx.x, t = threadIdx.x;
    if (t < 64) {
        float ch = fmaxf(fdec(chmax[t]), 1.0f);
        scl[t] = ch * (1.f / 127.f);
        if (d == 0) sinv[t] = 127.f / ch;
    }
    __syncthreads();
    float m = 0.f;
    for (int i = t; i < 1728; i += 256) m = fmaxf(m, fabsf(wcv[i * 64 + d]) * scl[i & 63]);
#pragma unroll
    for (int dd = 1; dd < 64; dd <<= 1) m = fmaxf(m, __shfl_xor(m, dd));
    if ((t & 63) == 0) red[t >> 6] = m;
    __syncthreads();
    if (t == 0) {
        float mm = fmaxf(fmaxf(red[0], red[1]), fmaxf(red[2], red[3]));
        tds = 127.f / fmaxf(mm, 1e-20f);
    }
    __syncthreads();
    float T = tds;
    for (int i = t; i < 1728; i += 256) {
        int k = i >> 6, c = i & 63;
        float v = wcv[i * 64 + d] * scl[c] * T;
        w8[k * 4096 + d * 64 + c] = (signed char)(int)rintf(v);
    }
}

// ---- BN1 + ELU + per-CHANNEL int8 quant, in place (4 lanes per row) ----
__global__ __launch_bounds__(256) void bn_elu_quant(char* __restrict__ ybuf,
                                                    const float* __restrict__ ab,
                                                    const float* __restrict__ sinv) {
    int gt = blockIdx.x * 256 + threadIdx.x;
    int row = gt >> 2, q = gt & 3;
    int c0 = q * 16;
    const __bf16* yr = (const __bf16*)(ybuf + (size_t)row * 128) + c0;
    bf16x8 h0 = *(const bf16x8*)(yr);
    bf16x8 h1 = *(const bf16x8*)(yr + 8);
    float v[16];
#pragma unroll
    for (int j = 0; j < 8; ++j) {
        float f = (float)h0[j] * ab[c0 + j] + ab[64 + c0 + j];
        v[j] = elu_f(f) * sinv[c0 + j];
    }
#pragma unroll
    for (int j = 0; j < 8; ++j) {
        float f = (float)h1[j] * ab[c0 + 8 + j] + ab[64 + c0 + 8 + j];
        v[8 + j] = elu_f(f) * sinv[c0 + 8 + j];
    }
    i32x4 pk;
#pragma unroll
    for (int w = 0; w < 4; ++w) {
        int acc = 0;
#pragma unroll
        for (int j = 0; j < 4; ++j) {
            int qv = (int)rintf(v[w * 4 + j]);
            acc |= (qv & 255) << (8 * j);
        }
        pk[w] = acc;
    }
    *(i32x4*)(ybuf + (size_t)row * 128 + q * 16) = pk;
}

// ---- kernel C: 27-tap gather conv, direct-register gathers, i32 accum ----
// 256 thr = 4 waves; wave owns 32 rows (2 m-tiles) x 64 cols. No scales.
// Stage = 2 A-gathers + 4 B-loads = 6 VMEM ops; 2-deep, steady vmcnt(6).
__global__ __launch_bounds__(256, 4) void conv_bn_stats(
    const char* __restrict__ ybuf, const int* __restrict__ neigh,
    const signed char* __restrict__ w8,
    float* __restrict__ out, float* __restrict__ bins) {
    __shared__ __align__(16) int idxb_s[4][32 * TAPS];
    __shared__ float ssum[64], ssq[64];
    int tid = threadIdx.x;
    int wave = tid >> 6, lane = tid & 63, lr = lane & 15, lg = lane >> 4;
    int wr0 = blockIdx.x * 128 + wave * 32;

    if (tid < 64) { ssum[tid] = 0.f; ssq[tid] = 0.f; }

    int* idxb = idxb_s[wave];

    // ---- stage this wave's 32x27 neighbor indices into LDS (coalesced) ----
    {
        int base_w = wr0 * TAPS;
#pragma unroll
        for (int j = 0; j < 14; ++j) {
            int w = j * 64 + lane;
            if (w < 32 * TAPS) idxb[w] = neigh[base_w + w];
        }
    }
    asm volatile("s_waitcnt vmcnt(0) lgkmcnt(0)" ::: "memory");
    __builtin_amdgcn_sched_barrier(0);

    i32x4 iacc[2][4];
#pragma unroll
    for (int mt = 0; mt < 2; ++mt)
#pragma unroll
        for (int nt = 0; nt < 4; ++nt) iacc[mt][nt] = (i32x4){0, 0, 0, 0};

    const signed char* w8l = w8 + lr * 64 + lg * 16;   // B-fragment base

    i32x4 abuf[2][2];
    i32x4 bbuf[2][4];
    int icur[2];

    // ---- prologue: stage 0 then stage 1 (6 VMEM ops each) ----
    {
        int i00 = idxb[lr * TAPS + 0], i01 = idxb[(16 + lr) * TAPS + 0];
        abuf[0][0] = *(const i32x4*)(ybuf + (size_t)(unsigned)i00 * 128 + lg * 16);
        abuf[0][1] = *(const i32x4*)(ybuf + (size_t)(unsigned)i01 * 128 + lg * 16);
#pragma unroll
        for (int nt = 0; nt < 4; ++nt) bbuf[0][nt] = *(const i32x4*)(w8l + nt * 1024);
        __builtin_amdgcn_sched_barrier(0);
        int i10 = idxb[lr * TAPS + 1], i11 = idxb[(16 + lr) * TAPS + 1];
        abuf[1][0] = *(const i32x4*)(ybuf + (size_t)(unsigned)i10 * 128 + lg * 16);
        abuf[1][1] = *(const i32x4*)(ybuf + (size_t)(unsigned)i11 * 128 + lg * 16);
#pragma unroll
        for (int nt = 0; nt < 4; ++nt) bbuf[1][nt] = *(const i32x4*)(w8l + 4096 + nt * 1024);
        __builtin_amdgcn_sched_barrier(0);
        icur[0] = idxb[lr * TAPS + 2];
        icur[1] = idxb[(16 + lr) * TAPS + 2];
    }

#pragma unroll
    for (int k = 0; k < TAPS; ++k) {
        const int p = k & 1;
        // 1. wait: stage k complete; stage k+1 (6 ops) may remain in flight
        if (k < TAPS - 1) { asm volatile("s_waitcnt vmcnt(6)" ::: "memory"); }
        else              { asm volatile("s_waitcnt vmcnt(0)" ::: "memory"); }
        __builtin_amdgcn_sched_barrier(0);
        // 2. MFMAs accumulate i32 directly (no dequant)
#pragma unroll
        for (int nt = 0; nt < 4; ++nt) {
            iacc[0][nt] = __builtin_amdgcn_mfma_i32_16x16x64_i8(abuf[p][0], bbuf[p][nt], iacc[0][nt], 0, 0, 0);
            iacc[1][nt] = __builtin_amdgcn_mfma_i32_16x16x64_i8(abuf[p][1], bbuf[p][nt], iacc[1][nt], 0, 0, 0);
        }
        // 3. issue stage k+2 into buffers just consumed (WAR-safe)
        if (k + 2 < TAPS) {
            abuf[p][0] = *(const i32x4*)(ybuf + (size_t)(unsigned)icur[0] * 128 + lg * 16);
            abuf[p][1] = *(const i32x4*)(ybuf + (size_t)(unsigned)icur[1] * 128 + lg * 16);
#pragma unroll
            for (int nt = 0; nt < 4; ++nt)
                bbuf[p][nt] = *(const i32x4*)(w8l + (k + 2) * 4096 + nt * 1024);
            if (k + 3 < TAPS) {
                icur[0] = idxb[lr * TAPS + (k + 3)];
                icur[1] = idxb[(16 + lr) * TAPS + (k + 3)];
            }
        }
    }

    // epilogue: raw scaled acc (column factor T_d cancels in BN2)
    float lsum[4] = {0.f, 0.f, 0.f, 0.f}, lsq[4] = {0.f, 0.f, 0.f, 0.f};
#pragma unroll
    for (int mt = 0; mt < 2; ++mt)
#pragma unroll
        for (int nt = 0; nt < 4; ++nt)
#pragma unroll
            for (int r = 0; r < 4; ++r) {
                float v = (float)iacc[mt][nt][r];
                int row = wr0 + mt * 16 + lg * 4 + r;
                out[(size_t)row * C_OUT + nt * 16 + lr] = v;
                lsum[nt] += v; lsq[nt] += v * v;
            }
    __syncthreads();
#pragma unroll
    for (int nt = 0; nt < 4; ++nt) {
        atomicAdd(&ssum[nt * 16 + lr], lsum[nt]);
        atomicAdd(&ssq[nt * 16 + lr], lsq[nt]);
    }
    __syncthreads();
    if (tid < 64) {
        float* b = bins + (size_t)(blockIdx.x & (NBINS - 1)) * 128;
        atomicAdd(&b[tid], ssum[tid]);
        atomicAdd(&b[64 + tid], ssq[tid]);
    }
}

// ---- BN2 + ELU applied in place on f32 d_out ----
__global__ __launch_bounds__(256) void bn_elu_out(float* __restrict__ out,
                                                  const float* __restrict__ ab) {
    int tid = blockIdx.x * 256 + threadIdx.x;
    int c0 = (tid * 4) & 63;
    float av[4], bv[4];
#pragma unroll
    for (int j = 0; j < 4; ++j) { av[j] = ab[c0 + j]; bv[j] = ab[64 + c0 + j]; }
#pragma unroll
    for (int t = 0; t < 8; ++t) {
        size_t e = ((size_t)t * 1048576 + tid) * 4;
        f32x4 v = *(const f32x4*)(out + e);
        f32x4 o;
#pragma unroll
        for (int j = 0; j < 4; ++j) o[j] = elu_f(v[j] * av[j] + bv[j]);
        *(f32x4*)(out + e) = o;
    }
}

extern "C" void kernel_launch(void* const* d_in, const int* in_sizes, int n_in,
                              void* d_out, int out_size, void* d_ws, size_t ws_size,
                              hipStream_t stream) {
    const float* x     = (const float*)d_in[0];
    const int*   neigh = (const int*)d_in[1];
    const float* wup   = (const float*)d_in[2];
    const float* wcv   = (const float*)d_in[3];
    const float* g1    = (const float*)d_in[4];
    const float* b1    = (const float*)d_in[5];
    const float* g2    = (const float*)d_in[6];
    const float* b2    = (const float*)d_in[7];
    float* out = (float*)d_out;

    char* ws = (char*)d_ws;
    char*        ybuf  = ws + Y_OFF;
    __bf16*      wtup  = (__bf16*)(ws + WTUP_OFF);
    signed char* w8    = (signed char*)(ws + W8CV_OFF);
    unsigned*    chmax = (unsigned*)(ws + CHMAX_OFF);
    float*       sinv  = (float*)(ws + SINV_OFF);
    float*       bins1 = (float*)(ws + S1_OFF);
    float*       bins2 = (float*)(ws + S2_OFF);
    float*       ab1   = (float*)(ws + AB1_OFF);
    float*       ab2   = (float*)(ws + AB2_OFF);

    hipMemsetAsync(ws + CHMAX_OFF, 0, ZERO_LEN, stream);

    prep_wup<<<256, 256, 0, stream>>>(wup, wtup);
    deconv_bn_stats<<<N_PARENT / 16, 256, 0, stream>>>(x, wtup, (__bf16*)ybuf, bins1);
    finalize_stats<<<1, 64, 0, stream>>>(bins1, g1, b1, ab1, 1.f / (float)N_CHILD);
    bn_max<<<4096, 256, 0, stream>>>((const __bf16*)ybuf, ab1, chmax);
    prep_w8<<<64, 256, 0, stream>>>(wcv, chmax, w8, sinv);
    bn_elu_quant<<<8192, 256, 0, stream>>>(ybuf, ab1, sinv);
    conv_bn_stats<<<N_CHILD / 128, 256, 0, stream>>>(ybuf, neigh, w8, out, bins2);
    finalize_stats<<<1, 64, 0, stream>>>(bins2, g2, b2, ab2, 1.f / (float)N_CHILD);
    bn_elu_out<<<4096, 256, 0, stream>>>(out, ab2);
}

// Round 9
// 465.787 us; speedup vs baseline: 1.1474x; 1.1474x over previous
//
#include <hip/hip_runtime.h>

// UpBlock: deconv(8-oct GEMM) -> BN+ELU -> 27-tap gather conv -> BN+ELU
// R9: fold per-channel h min/max tracking into deconv epilogue (removes the
// bn_max pass, whose LDS/global atomic serialization cost ~90 us). chabs from
// monotone ELU(affine) of (hmin,hmax) + 1.005 margin + clamp in quant.

#define N_PARENT 65536
#define C_IN     128
#define C_OUT    64
#define N_CHILD  (N_PARENT * 8)
#define TAPS     27
#define NBINS    64

typedef __bf16 bf16x8 __attribute__((ext_vector_type(8)));
typedef float  f32x4  __attribute__((ext_vector_type(4)));
typedef int    i32x4  __attribute__((ext_vector_type(4)));

// workspace layout (bytes)
#define Y_OFF     0u          // rows [N_CHILD][128B]: bf16 h, then int8 y8 in first 64B
#define WTUP_OFF  67108864u   // bf16 WtUp [8][64 n][128 k] = 131072
#define W8CV_OFF  67239936u   // i8 Wt8 [27][64 d][64 c] = 110592
#define CHMAX_OFF 67350528u   // u32 keyed per-channel max of h [64] = 256
#define CHMIN_OFF 67350784u   // u32 keyed per-channel min of h [64] = 256
#define SINV_OFF  67351040u   // f32 127/chabs [64] = 256
#define SCL_OFF   67351296u   // f32 chabs/127 [64] = 256
#define S1_OFF    67351552u   // f32 bins1 [64][128] = 32768
#define S2_OFF    67384320u   // f32 bins2 [64][128] = 32768
#define AB1_OFF   67417088u   // f32 a1[64], b1[64] = 512
#define AB2_OFF   67417600u   // f32 a2[64], b2[64] = 512
#define ZERO_LEN  (67418112u - CHMAX_OFF)

__device__ __forceinline__ float elu_f(float f) {
    return f > 0.f ? f : (__expf(f) - 1.f);
}
// order-preserving float<->uint key for atomic max/min on signed floats
__device__ __forceinline__ unsigned fkey(float f) {
    unsigned b = __float_as_uint(f);
    return (b & 0x80000000u) ? ~b : (b | 0x80000000u);
}
__device__ __forceinline__ float fdec(unsigned k) {
    unsigned b = (k & 0x80000000u) ? (k & 0x7fffffffu) : ~k;
    return __uint_as_float(b);
}

// ---- prep: WtUp transpose -> bf16 [8][64 n][128 k] ----
__global__ __launch_bounds__(256) void prep_wup(const float* __restrict__ wup,
                                                __bf16* __restrict__ wtup) {
    int i = blockIdx.x * 256 + threadIdx.x;        // 65536
    int o = i >> 13, rem = i & 8191, n = rem >> 7, k = rem & 127;
    wtup[i] = (__bf16)wup[o * 8192 + k * 64 + n];
}

// ---- kernel A: h[8p+oct] = x[p] @ W_up[oct] (bf16), BN1 stats + h min/max ----
__global__ __launch_bounds__(256) void deconv_bn_stats(
    const float* __restrict__ x, const __bf16* __restrict__ wtup,
    __bf16* __restrict__ y, float* __restrict__ bins,
    unsigned* __restrict__ chmax, unsigned* __restrict__ chmin) {
    __shared__ float ssum[64], ssq[64];
    __shared__ unsigned smax[64], smin[64];
    int tid = threadIdx.x;
    int wave = tid >> 6, lane = tid & 63, lr = lane & 15, lg = lane >> 4;
    int p0 = blockIdx.x * 16;

    if (tid < 64) { ssum[tid] = 0.f; ssq[tid] = 0.f; smax[tid] = 0u; smin[tid] = 0xFFFFFFFFu; }

    const float* xrow = x + (size_t)(p0 + lr) * C_IN;
    bf16x8 afr[4];
#pragma unroll
    for (int ks = 0; ks < 4; ++ks) {
        const float* src = xrow + ks * 32 + lg * 8;
        f32x4 u0 = *(const f32x4*)(src);
        f32x4 u1 = *(const f32x4*)(src + 4);
        bf16x8 a;
#pragma unroll
        for (int i = 0; i < 4; ++i) { a[i] = (__bf16)u0[i]; a[4 + i] = (__bf16)u1[i]; }
        afr[ks] = a;
    }

    float lsum[4] = {0.f, 0.f, 0.f, 0.f}, lsq[4] = {0.f, 0.f, 0.f, 0.f};
    float hx[4] = {-3e38f, -3e38f, -3e38f, -3e38f};
    float hn[4] = {3e38f, 3e38f, 3e38f, 3e38f};
#pragma unroll
    for (int oo = 0; oo < 2; ++oo) {
        int oct = wave * 2 + oo;
#pragma unroll
        for (int nt = 0; nt < 4; ++nt) {
            f32x4 acc = {0.f, 0.f, 0.f, 0.f};
#pragma unroll
            for (int ks = 0; ks < 4; ++ks) {
                const __bf16* bp = wtup + ((size_t)(oct * 64 + nt * 16 + lr) * C_IN + ks * 32 + lg * 8);
                bf16x8 b = *(const bf16x8*)bp;
                acc = __builtin_amdgcn_mfma_f32_16x16x32_bf16(afr[ks], b, acc, 0, 0, 0);
            }
#pragma unroll
            for (int r = 0; r < 4; ++r) {
                int parent = p0 + lg * 4 + r;
                int child = parent * 8 + oct;
                float v = acc[r];
                y[(size_t)child * 64 + nt * 16 + lr] = (__bf16)v;
                lsum[nt] += v; lsq[nt] += v * v;
                hx[nt] = fmaxf(hx[nt], v); hn[nt] = fminf(hn[nt], v);
            }
        }
    }
    __syncthreads();
#pragma unroll
    for (int nt = 0; nt < 4; ++nt) {
        atomicAdd(&ssum[nt * 16 + lr], lsum[nt]);
        atomicAdd(&ssq[nt * 16 + lr], lsq[nt]);
        atomicMax(&smax[nt * 16 + lr], fkey(hx[nt]));
        atomicMin(&smin[nt * 16 + lr], fkey(hn[nt]));
    }
    __syncthreads();
    if (tid < 64) {
        float* b = bins + (size_t)(blockIdx.x & (NBINS - 1)) * 128;
        atomicAdd(&b[tid], ssum[tid]);
        atomicAdd(&b[64 + tid], ssq[tid]);
        atomicMax(&chmax[tid], smax[tid]);
        atomicMin(&chmin[tid], smin[tid]);
    }
}

// ---- finalize BN1: ab = (a,b), plus quant range from h min/max ----
__global__ void finalize_bn1(const float* __restrict__ bins,
                             const float* __restrict__ gamma,
                             const float* __restrict__ beta,
                             const unsigned* __restrict__ chmax,
                             const unsigned* __restrict__ chmin,
                             float* __restrict__ ab,
                             float* __restrict__ sinv, float* __restrict__ scl,
                             float invN) {
    int c = threadIdx.x;  // 64 threads
    float s = 0.f, q = 0.f;
    for (int b = 0; b < NBINS; ++b) { s += bins[b * 128 + c]; q += bins[b * 128 + 64 + c]; }
    float mu = s * invN;
    float var = q * invN - mu * mu;
    float rstd = rsqrtf(var + 1e-5f);
    float a = gamma[c] * rstd;
    float b = beta[c] - mu * a;
    ab[c] = a;
    ab[64 + c] = b;
    float hmx = fdec(chmax[c]), hmn = fdec(chmin[c]);
    float t0 = a * hmx + b, t1 = a * hmn + b;
    float fhi = elu_f(fmaxf(t0, t1));
    float flo = elu_f(fminf(t0, t1));
    float chabs = fmaxf(fmaxf(fhi, -flo), 1e-6f) * 1.005f;  // bf16-rounding margin
    sinv[c] = 127.f / chabs;
    scl[c] = chabs * (1.f / 127.f);
}

// ---- finalize BN2: per-channel a = gamma*rstd, b = beta - mu*a ----
__global__ void finalize_stats(const float* __restrict__ bins,
                               const float* __restrict__ gamma,
                               const float* __restrict__ beta,
                               float* __restrict__ ab, float invN) {
    int c = threadIdx.x;  // 64 threads
    float s = 0.f, q = 0.f;
    for (int b = 0; b < NBINS; ++b) { s += bins[b * 128 + c]; q += bins[b * 128 + 64 + c]; }
    float mu = s * invN;
    float var = q * invN - mu * mu;
    float rstd = rsqrtf(var + 1e-5f);
    float a = gamma[c] * rstd;
    ab[c] = a;
    ab[64 + c] = beta[c] - mu * a;
}

// ---- prep_w8: fold per-channel y scale into int8 W_conv ----
// w8[k][d][c] = round(wcv[k][c][d] * scl_c * T_d); T_d cancels in BN2.
__global__ __launch_bounds__(256) void prep_w8(const float* __restrict__ wcv,
                                               const float* __restrict__ scl,
                                               signed char* __restrict__ w8) {
    __shared__ float scl_s[64];
    __shared__ float red[4];
    __shared__ float tds;
    int d = blockIdx.x, t = threadIdx.x;
    if (t < 64) scl_s[t] = scl[t];
    __syncthreads();
    float m = 0.f;
    for (int i = t; i < 1728; i += 256) m = fmaxf(m, fabsf(wcv[i * 64 + d]) * scl_s[i & 63]);
#pragma unroll
    for (int dd = 1; dd < 64; dd <<= 1) m = fmaxf(m, __shfl_xor(m, dd));
    if ((t & 63) == 0) red[t >> 6] = m;
    __syncthreads();
    if (t == 0) {
        float mm = fmaxf(fmaxf(red[0], red[1]), fmaxf(red[2], red[3]));
        tds = 127.f / fmaxf(mm, 1e-20f);
    }
    __syncthreads();
    float T = tds;
    for (int i = t; i < 1728; i += 256) {
        int k = i >> 6, c = i & 63;
        float v = wcv[i * 64 + d] * scl_s[c] * T;
        w8[k * 4096 + d * 64 + c] = (signed char)(int)rintf(v);
    }
}

// ---- BN1 + ELU + per-CHANNEL int8 quant, in place (4 lanes per row) ----
__global__ __launch_bounds__(256) void bn_elu_quant(char* __restrict__ ybuf,
                                                    const float* __restrict__ ab,
                                                    const float* __restrict__ sinv) {
    int gt = blockIdx.x * 256 + threadIdx.x;
    int row = gt >> 2, q = gt & 3;
    int c0 = q * 16;
    const __bf16* yr = (const __bf16*)(ybuf + (size_t)row * 128) + c0;
    bf16x8 h0 = *(const bf16x8*)(yr);
    bf16x8 h1 = *(const bf16x8*)(yr + 8);
    float v[16];
#pragma unroll
    for (int j = 0; j < 8; ++j) {
        float f = (float)h0[j] * ab[c0 + j] + ab[64 + c0 + j];
        v[j] = elu_f(f) * sinv[c0 + j];
    }
#pragma unroll
    for (int j = 0; j < 8; ++j) {
        float f = (float)h1[j] * ab[c0 + 8 + j] + ab[64 + c0 + 8 + j];
        v[8 + j] = elu_f(f) * sinv[c0 + 8 + j];
    }
    i32x4 pk;
#pragma unroll
    for (int w = 0; w < 4; ++w) {
        int acc = 0;
#pragma unroll
        for (int j = 0; j < 4; ++j) {
            float vc = fminf(fmaxf(v[w * 4 + j], -127.f), 127.f);  // wrap guard
            int qv = (int)rintf(vc);
            acc |= (qv & 255) << (8 * j);
        }
        pk[w] = acc;
    }
    *(i32x4*)(ybuf + (size_t)row * 128 + q * 16) = pk;
}

// ---- kernel C: 27-tap gather conv, direct-register gathers, i32 accum ----
// 256 thr = 4 waves; wave owns 32 rows (2 m-tiles) x 64 cols. No scales.
// Stage = 2 A-gathers + 4 B-loads = 6 VMEM ops; 2-deep, steady vmcnt(6).
__global__ __launch_bounds__(256, 4) void conv_bn_stats(
    const char* __restrict__ ybuf, const int* __restrict__ neigh,
    const signed char* __restrict__ w8,
    float* __restrict__ out, float* __restrict__ bins) {
    __shared__ __align__(16) int idxb_s[4][32 * TAPS];
    __shared__ float ssum[64], ssq[64];
    int tid = threadIdx.x;
    int wave = tid >> 6, lane = tid & 63, lr = lane & 15, lg = lane >> 4;
    int wr0 = blockIdx.x * 128 + wave * 32;

    if (tid < 64) { ssum[tid] = 0.f; ssq[tid] = 0.f; }

    int* idxb = idxb_s[wave];

    // ---- stage this wave's 32x27 neighbor indices into LDS (coalesced) ----
    {
        int base_w = wr0 * TAPS;
#pragma unroll
        for (int j = 0; j < 14; ++j) {
            int w = j * 64 + lane;
            if (w < 32 * TAPS) idxb[w] = neigh[base_w + w];
        }
    }
    asm volatile("s_waitcnt vmcnt(0) lgkmcnt(0)" ::: "memory");
    __builtin_amdgcn_sched_barrier(0);

    i32x4 iacc[2][4];
#pragma unroll
    for (int mt = 0; mt < 2; ++mt)
#pragma unroll
        for (int nt = 0; nt < 4; ++nt) iacc[mt][nt] = (i32x4){0, 0, 0, 0};

    const signed char* w8l = w8 + lr * 64 + lg * 16;   // B-fragment base

    i32x4 abuf[2][2];
    i32x4 bbuf[2][4];
    int icur[2];

    // ---- prologue: stage 0 then stage 1 (6 VMEM ops each) ----
    {
        int i00 = idxb[lr * TAPS + 0], i01 = idxb[(16 + lr) * TAPS + 0];
        abuf[0][0] = *(const i32x4*)(ybuf + (size_t)(unsigned)i00 * 128 + lg * 16);
        abuf[0][1] = *(const i32x4*)(ybuf + (size_t)(unsigned)i01 * 128 + lg * 16);
#pragma unroll
        for (int nt = 0; nt < 4; ++nt) bbuf[0][nt] = *(const i32x4*)(w8l + nt * 1024);
        __builtin_amdgcn_sched_barrier(0);
        int i10 = idxb[lr * TAPS + 1], i11 = idxb[(16 + lr) * TAPS + 1];
        abuf[1][0] = *(const i32x4*)(ybuf + (size_t)(unsigned)i10 * 128 + lg * 16);
        abuf[1][1] = *(const i32x4*)(ybuf + (size_t)(unsigned)i11 * 128 + lg * 16);
#pragma unroll
        for (int nt = 0; nt < 4; ++nt) bbuf[1][nt] = *(const i32x4*)(w8l + 4096 + nt * 1024);
        __builtin_amdgcn_sched_barrier(0);
        icur[0] = idxb[lr * TAPS + 2];
        icur[1] = idxb[(16 + lr) * TAPS + 2];
    }

#pragma unroll
    for (int k = 0; k < TAPS; ++k) {
        const int p = k & 1;
        // 1. wait: stage k complete; stage k+1 (6 ops) may remain in flight
        if (k < TAPS - 1) { asm volatile("s_waitcnt vmcnt(6)" ::: "memory"); }
        else              { asm volatile("s_waitcnt vmcnt(0)" ::: "memory"); }
        __builtin_amdgcn_sched_barrier(0);
        // 2. MFMAs accumulate i32 directly (no dequant)
#pragma unroll
        for (int nt = 0; nt < 4; ++nt) {
            iacc[0][nt] = __builtin_amdgcn_mfma_i32_16x16x64_i8(abuf[p][0], bbuf[p][nt], iacc[0][nt], 0, 0, 0);
            iacc[1][nt] = __builtin_amdgcn_mfma_i32_16x16x64_i8(abuf[p][1], bbuf[p][nt], iacc[1][nt], 0, 0, 0);
        }
        // 3. issue stage k+2 into buffers just consumed (WAR-safe)
        if (k + 2 < TAPS) {
            abuf[p][0] = *(const i32x4*)(ybuf + (size_t)(unsigned)icur[0] * 128 + lg * 16);
            abuf[p][1] = *(const i32x4*)(ybuf + (size_t)(unsigned)icur[1] * 128 + lg * 16);
#pragma unroll
            for (int nt = 0; nt < 4; ++nt)
                bbuf[p][nt] = *(const i32x4*)(w8l + (k + 2) * 4096 + nt * 1024);
            if (k + 3 < TAPS) {
                icur[0] = idxb[lr * TAPS + (k + 3)];
                icur[1] = idxb[(16 + lr) * TAPS + (k + 3)];
            }
        }
    }

    // epilogue: raw scaled acc (column factor T_d cancels in BN2)
    float lsum[4] = {0.f, 0.f, 0.f, 0.f}, lsq[4] = {0.f, 0.f, 0.f, 0.f};
#pragma unroll
    for (int mt = 0; mt < 2; ++mt)
#pragma unroll
        for (int nt = 0; nt < 4; ++nt)
#pragma unroll
            for (int r = 0; r < 4; ++r) {
                float v = (float)iacc[mt][nt][r];
                int row = wr0 + mt * 16 + lg * 4 + r;
                out[(size_t)row * C_OUT + nt * 16 + lr] = v;
                lsum[nt] += v; lsq[nt] += v * v;
            }
    __syncthreads();
#pragma unroll
    for (int nt = 0; nt < 4; ++nt) {
        atomicAdd(&ssum[nt * 16 + lr], lsum[nt]);
        atomicAdd(&ssq[nt * 16 + lr], lsq[nt]);
    }
    __syncthreads();
    if (tid < 64) {
        float* b = bins + (size_t)(blockIdx.x & (NBINS - 1)) * 128;
        atomicAdd(&b[tid], ssum[tid]);
        atomicAdd(&b[64 + tid], ssq[tid]);
    }
}

// ---- BN2 + ELU applied in place on f32 d_out ----
__global__ __launch_bounds__(256) void bn_elu_out(float* __restrict__ out,
                                                  const float* __restrict__ ab) {
    int tid = blockIdx.x * 256 + threadIdx.x;
    int c0 = (tid * 4) & 63;
    float av[4], bv[4];
#pragma unroll
    for (int j = 0; j < 4; ++j) { av[j] = ab[c0 + j]; bv[j] = ab[64 + c0 + j]; }
#pragma unroll
    for (int t = 0; t < 8; ++t) {
        size_t e = ((size_t)t * 1048576 + tid) * 4;
        f32x4 v = *(const f32x4*)(out + e);
        f32x4 o;
#pragma unroll
        for (int j = 0; j < 4; ++j) o[j] = elu_f(v[j] * av[j] + bv[j]);
        *(f32x4*)(out + e) = o;
    }
}

extern "C" void kernel_launch(void* const* d_in, const int* in_sizes, int n_in,
                              void* d_out, int out_size, void* d_ws, size_t ws_size,
                              hipStream_t stream) {
    const float* x     = (const float*)d_in[0];
    const int*   neigh = (const int*)d_in[1];
    const float* wup   = (const float*)d_in[2];
    const float* wcv   = (const float*)d_in[3];
    const float* g1    = (const float*)d_in[4];
    const float* b1    = (const float*)d_in[5];
    const float* g2    = (const float*)d_in[6];
    const float* b2    = (const float*)d_in[7];
    float* out = (float*)d_out;

    char* ws = (char*)d_ws;
    char*        ybuf  = ws + Y_OFF;
    __bf16*      wtup  = (__bf16*)(ws + WTUP_OFF);
    signed char* w8    = (signed char*)(ws + W8CV_OFF);
    unsigned*    chmax = (unsigned*)(ws + CHMAX_OFF);
    unsigned*    chmin = (unsigned*)(ws + CHMIN_OFF);
    float*       sinv  = (float*)(ws + SINV_OFF);
    float*       scl   = (float*)(ws + SCL_OFF);
    float*       bins1 = (float*)(ws + S1_OFF);
    float*       bins2 = (float*)(ws + S2_OFF);
    float*       ab1   = (float*)(ws + AB1_OFF);
    float*       ab2   = (float*)(ws + AB2_OFF);

    hipMemsetAsync(ws + CHMAX_OFF, 0, ZERO_LEN, stream);
    hipMemsetAsync(ws + CHMIN_OFF, 0xFF, 256, stream);   // chmin init = +inf key

    prep_wup<<<256, 256, 0, stream>>>(wup, wtup);
    deconv_bn_stats<<<N_PARENT / 16, 256, 0, stream>>>(x, wtup, (__bf16*)ybuf, bins1, chmax, chmin);
    finalize_bn1<<<1, 64, 0, stream>>>(bins1, g1, b1, chmax, chmin, ab1, sinv, scl, 1.f / (float)N_CHILD);
    prep_w8<<<64, 256, 0, stream>>>(wcv, scl, w8);
    bn_elu_quant<<<8192, 256, 0, stream>>>(ybuf, ab1, sinv);
    conv_bn_stats<<<N_CHILD / 128, 256, 0, stream>>>(ybuf, neigh, w8, out, bins2);
    finalize_stats<<<1, 64, 0, stream>>>(bins2, g2, b2, ab2, 1.f / (float)N_CHILD);
    bn_elu_out<<<4096, 256, 0, stream>>>(out, ab2);
}